// Round 2
// baseline (3969.547 us; speedup 1.0000x reference)
//
#include <hip/hip_runtime.h>

#define SEQ   120
#define WARM  96
#define FLEN  24
#define HDIM  256
#define MROWS 16

typedef __attribute__((ext_vector_type(8))) short bf16x8;
typedef __attribute__((ext_vector_type(4))) float floatx4;

// ws layout (bytes):
//   [0, 512K)       whi  bf16 [1024][256]   (row-major, k contiguous = B-operand layout)
//   [512K, 1M)      wlo  bf16 [1024][256]
//   [1M, 1M+4K)     bb   f32  [1024]        (b_ih + b_hh)
//   [1M+4K, 1M+8K)  wi   f32  [1024]        (W_ih column)
#define WHI_OFF 0
#define WLO_OFF (512 * 1024)
#define BB_OFF  (1024 * 1024)
#define WI_OFF  (1024 * 1024 + 4096)

__device__ __forceinline__ short f2bf(float v) {
    unsigned u = __float_as_uint(v);
    u += 0x7FFF + ((u >> 16) & 1);           // round-to-nearest-even
    return (short)(u >> 16);
}
__device__ __forceinline__ float bf2f(short s) {
    return __uint_as_float(((unsigned)(unsigned short)s) << 16);
}
__device__ __forceinline__ float fast_sig(float x) {
    return 1.0f / (1.0f + __expf(-x));
}
__device__ __forceinline__ float fast_tanh(float x) {
    return 1.0f - 2.0f / (__expf(2.0f * x) + 1.0f);
}

__global__ __launch_bounds__(256) void lstm_prep(
    const float* __restrict__ W_ih, const float* __restrict__ W_hh,
    const float* __restrict__ b_ih, const float* __restrict__ b_hh,
    unsigned char* __restrict__ ws)
{
    short* whi = (short*)(ws + WHI_OFF);
    short* wlo = (short*)(ws + WLO_OFF);
    float* bb  = (float*)(ws + BB_OFF);
    float* wi  = (float*)(ws + WI_OFF);
    int tid = blockIdx.x * 256 + threadIdx.x;
    if (tid < 1024 * 256) {
        float v  = W_hh[tid];
        short hi = f2bf(v);
        whi[tid] = hi;
        wlo[tid] = f2bf(v - bf2f(hi));
    }
    if (tid < 1024) {
        bb[tid] = b_ih[tid] + b_hh[tid];
        wi[tid] = W_ih[tid];
    }
}

__global__ __launch_bounds__(256, 1) void lstm_mfma(
    const float* __restrict__ x, const float* __restrict__ h0,
    const float* __restrict__ c0, const unsigned char* __restrict__ ws,
    const float* __restrict__ fcw, const float* __restrict__ fcb,
    float* __restrict__ out)
{
    // LDS: hhi/hlo pitch 264 shorts (pad 8 -> 2-way-max bank aliasing on b128 reads)
    __shared__ short hhi[MROWS * 264];
    __shared__ short hlo[MROWS * 264];
    __shared__ float gates[MROWS * 1025];    // pitch 1025 -> conflict-free rd/wr
    __shared__ float x_s[MROWS * SEQ];
    __shared__ float part[4][MROWS];
    __shared__ float yb[MROWS];

    const short* whi = (const short*)(ws + WHI_OFF);
    const short* wlo = (const short*)(ws + WLO_OFF);
    const float* bb  = (const float*)(ws + BB_OFF);
    const float* wi  = (const float*)(ws + WI_OFF);

    const int t    = threadIdx.x;
    const int wave = t >> 6;
    const int lane = t & 63;
    const int quad = lane >> 4;
    const int nof  = lane & 15;
    const int j    = t;                       // hidden unit owned in elementwise phase
    const int r0   = blockIdx.x * MROWS;

    // ---- init ----
    float c[MROWS];
    #pragma unroll
    for (int r = 0; r < MROWS; ++r) {
        float h = h0[(r0 + r) * HDIM + j];
        short hi = f2bf(h);
        hhi[r * 264 + j] = hi;
        hlo[r * 264 + j] = f2bf(h - bf2f(hi));
        c[r] = c0[(r0 + r) * HDIM + j];
    }
    for (int idx = t; idx < MROWS * SEQ; idx += 256) {
        int r = idx / SEQ, s = idx % SEQ;
        x_s[r * SEQ + s] = x[(r0 + r) * SEQ + s];
    }
    // per-thread constants for elementwise phase (unit j, 4 gates)
    float bb4[4], wi4[4];
    #pragma unroll
    for (int g = 0; g < 4; ++g) { bb4[g] = bb[g * 256 + j]; wi4[g] = wi[g * 256 + j]; }
    const float fcwj = fcw[j];
    const float fcb0 = fcb[0];

    // per-wave W pointers: wave owns cols [256*wave, 256*wave+256) = gate `wave`
    const int cb = wave * 256;
    const short* __restrict__ pwhi = whi + (cb + nof) * HDIM + quad * 8;
    const short* __restrict__ pwlo = wlo + (cb + nof) * HDIM + quad * 8;

    __syncthreads();

    for (int step = 0; step < SEQ; ++step) {
        // ================= MFMA phase: gates = h @ W^T (3-pass hi/lo) =========
        floatx4 acc[16];
        #pragma unroll
        for (int nt = 0; nt < 16; ++nt) acc[nt] = (floatx4){0.f, 0.f, 0.f, 0.f};

        #pragma unroll 1
        for (int kt = 0; kt < 8; ++kt) {
            const int k0 = kt * 32;
            bf16x8 ahi = *(const bf16x8*)&hhi[nof * 264 + k0 + quad * 8];
            bf16x8 alo = *(const bf16x8*)&hlo[nof * 264 + k0 + quad * 8];
            #pragma unroll
            for (int nt = 0; nt < 16; ++nt) {
                bf16x8 bhi = *(const bf16x8*)(pwhi + nt * 16 * HDIM + k0);
                bf16x8 blo = *(const bf16x8*)(pwlo + nt * 16 * HDIM + k0);
                acc[nt] = __builtin_amdgcn_mfma_f32_16x16x32_bf16(ahi, bhi, acc[nt], 0, 0, 0);
                acc[nt] = __builtin_amdgcn_mfma_f32_16x16x32_bf16(alo, bhi, acc[nt], 0, 0, 0);
                acc[nt] = __builtin_amdgcn_mfma_f32_16x16x32_bf16(ahi, blo, acc[nt], 0, 0, 0);
            }
        }
        // epilogue: C frag (col=lane&15, row=quad*4+reg) -> gates LDS
        #pragma unroll
        for (int nt = 0; nt < 16; ++nt) {
            const int col = cb + nt * 16 + nof;
            #pragma unroll
            for (int rg = 0; rg < 4; ++rg)
                gates[(quad * 4 + rg) * 1025 + col] = acc[nt][rg];
        }

        __syncthreads();   // (a) gates ready; h reads done

        // ================= elementwise: thread j owns unit j ==================
        const bool needy = (step >= WARM - 1);
        float v[MROWS];
        #pragma unroll
        for (int r = 0; r < MROWS; ++r) {
            const float inr = (step < WARM) ? x_s[r * SEQ + step] : yb[r];
            float g0 = gates[r * 1025 +         j] + bb4[0] + inr * wi4[0];
            float g1 = gates[r * 1025 + 256 + j] + bb4[1] + inr * wi4[1];
            float g2 = gates[r * 1025 + 512 + j] + bb4[2] + inr * wi4[2];
            float g3 = gates[r * 1025 + 768 + j] + bb4[3] + inr * wi4[3];
            float ig = fast_sig(g0);
            float fg = fast_sig(g1);
            float gg = fast_tanh(g2);
            float og = fast_sig(g3);
            float cn = fg * c[r] + ig * gg;
            c[r] = cn;
            float h = og * fast_tanh(cn);
            short hi = f2bf(h);
            hhi[r * 264 + j] = hi;
            hlo[r * 264 + j] = f2bf(h - bf2f(hi));
            v[r] = fcwj * h;
        }

        // fc head (only needed from step WARM-1 on)
        if (needy) {
            #pragma unroll
            for (int off = 32; off > 0; off >>= 1) {
                #pragma unroll
                for (int r = 0; r < MROWS; ++r) v[r] += __shfl_xor(v[r], off, 64);
            }
            if (lane < MROWS) part[wave][lane] = v[lane];
        }

        __syncthreads();   // (b) h ready for next step; part ready

        if (needy && t < MROWS) {
            float yv = fcb0 + part[0][t] + part[1][t] + part[2][t] + part[3][t];
            yb[t] = yv;                                  // consumed after next bar (a)
            if (step >= WARM)
                out[(r0 + t) * FLEN + (step - WARM)] = yv;
        }
    }
}

extern "C" void kernel_launch(void* const* d_in, const int* in_sizes, int n_in,
                              void* d_out, int out_size, void* d_ws, size_t ws_size,
                              hipStream_t stream) {
    const float* x    = (const float*)d_in[0];
    const float* h0   = (const float*)d_in[1];
    const float* c0   = (const float*)d_in[2];
    const float* W_ih = (const float*)d_in[3];
    const float* W_hh = (const float*)d_in[4];
    const float* b_ih = (const float*)d_in[5];
    const float* b_hh = (const float*)d_in[6];
    const float* fc_w = (const float*)d_in[7];
    const float* fc_b = (const float*)d_in[8];
    float* out = (float*)d_out;
    unsigned char* ws = (unsigned char*)d_ws;

    lstm_prep<<<1024, 256, 0, stream>>>(W_ih, W_hh, b_ih, b_hh, ws);
    lstm_mfma<<<128, 256, 0, stream>>>(x, h0, c0, ws, fc_w, fc_b, out);
}

// Round 3
// 3724.813 us; speedup vs baseline: 1.0657x; 1.0657x over previous
//
#include <hip/hip_runtime.h>

#define SEQ   120
#define WARM  96
#define FLEN  24
#define HDIM  256
#define MROWS 16
#define PADP  264            // hhi/hlo pitch in shorts (528 B, 16B-aligned)

typedef __attribute__((ext_vector_type(8))) short bf16x8;
typedef __attribute__((ext_vector_type(4))) float floatx4;

// ws layout (bytes):
//   [0, 1M)         WB: [tile 0..63][kt 0..7][ hi 1KB | lo 1KB ]
//                   tile = (gate*16 + wave*2 + half); within 1KB: lane*16 + i*2
//   [1M, 1M+4K)     bb f32[1024]  (b_ih + b_hh)
//   [1M+4K, 1M+8K)  wi f32[1024]  (W_ih column)
#define WB_OFF 0
#define BB_OFF (1024 * 1024)
#define WI_OFF (1024 * 1024 + 4096)

__device__ __forceinline__ short f2bf(float v) {
    unsigned u = __float_as_uint(v);
    u += 0x7FFF + ((u >> 16) & 1);          // RNE
    return (short)(u >> 16);
}
__device__ __forceinline__ float bf2f(short s) {
    return __uint_as_float(((unsigned)(unsigned short)s) << 16);
}
__device__ __forceinline__ float fast_sig(float x) {
    return 1.0f / (1.0f + __expf(-x));
}
__device__ __forceinline__ float fast_tanh(float x) {
    return 1.0f - 2.0f / (__expf(2.0f * x) + 1.0f);
}

__global__ __launch_bounds__(256) void lstm_prep(
    const float* __restrict__ W_ih, const float* __restrict__ W_hh,
    const float* __restrict__ b_ih, const float* __restrict__ b_hh,
    unsigned char* __restrict__ ws)
{
    int tid = blockIdx.x * 256 + threadIdx.x;
    if (tid < 262144) {
        int r = tid >> 8, k = tid & 255;        // r = output col (gate*256+unit)
        float v  = W_hh[tid];
        short hi = f2bf(v);
        short lo = f2bf(v - bf2f(hi));
        int tile = r >> 4, nof = r & 15;
        int kt   = k >> 5, quad = (k >> 3) & 3, i = k & 7;
        size_t base = (size_t)tile * 16384 + (size_t)kt * 2048 + (quad * 16 + nof) * 16 + i * 2;
        *(short*)(ws + WB_OFF + base)        = hi;
        *(short*)(ws + WB_OFF + base + 1024) = lo;
    }
    if (tid < 1024) {
        ((float*)(ws + BB_OFF))[tid] = b_ih[tid] + b_hh[tid];
        ((float*)(ws + WI_OFF))[tid] = W_ih[tid];
    }
}

__global__ __launch_bounds__(512) void lstm_mfma(
    const float* __restrict__ x, const float* __restrict__ h0,
    const float* __restrict__ c0, const unsigned char* __restrict__ ws,
    const float* __restrict__ fcw, const float* __restrict__ fcb,
    float* __restrict__ out)
{
    __shared__ short hhi[MROWS * PADP];
    __shared__ short hlo[MROWS * PADP];
    __shared__ float x_s[MROWS * SEQ];
    __shared__ float part[8][MROWS];
    __shared__ float yb[MROWS];

    const int t    = threadIdx.x;
    const int wv   = t >> 6;
    const int lane = t & 63;
    const int quad = lane >> 4;
    const int nof  = lane & 15;
    const int r0   = blockIdx.x * MROWS;

    const unsigned char* wb = ws + WB_OFF;
    const float* bb = (const float*)(ws + BB_OFF);
    const float* wi = (const float*)(ws + WI_OFF);

    // columns owned by this lane in the elementwise phase
    const int u0 = wv * 32 + nof;
    const int u1 = u0 + 16;

    // ---- init state: c in C-fragment layout, h -> LDS hi/lo ----
    float c[2][4];
    #pragma unroll
    for (int hf = 0; hf < 2; ++hf) {
        const int u = hf ? u1 : u0;
        #pragma unroll
        for (int rg = 0; rg < 4; ++rg) {
            const int m = quad * 4 + rg;
            float h  = h0[(r0 + m) * HDIM + u];
            short hi = f2bf(h);
            hhi[m * PADP + u] = hi;
            hlo[m * PADP + u] = f2bf(h - bf2f(hi));
            c[hf][rg] = c0[(r0 + m) * HDIM + u];
        }
    }
    for (int idx = t; idx < MROWS * SEQ; idx += 512) {
        int m = idx / SEQ, s = idx % SEQ;
        x_s[m * SEQ + s] = x[(r0 + m) * SEQ + s];
    }
    float bbv[2][4], wiv[2][4];
    #pragma unroll
    for (int hf = 0; hf < 2; ++hf) {
        const int u = hf ? u1 : u0;
        #pragma unroll
        for (int g = 0; g < 4; ++g) {
            bbv[hf][g] = bb[g * 256 + u];
            wiv[hf][g] = wi[g * 256 + u];
        }
    }
    const float fcw0 = fcw[u0], fcw1 = fcw[u1];
    const float fcb0 = fcb[0];

    // per-nt W base pointers: nt = gate*2 + half
    const unsigned char* pB[8];
    #pragma unroll
    for (int nt = 0; nt < 8; ++nt) {
        int g = nt >> 1, hf = nt & 1;
        int tile = g * 16 + wv * 2 + hf;
        pB[nt] = wb + (size_t)tile * 16384 + lane * 16;
    }

    __syncthreads();

    for (int step = 0; step < SEQ; ++step) {
        // ============ MFMA phase: gates = h @ W^T (3-pass hi/lo) ============
        floatx4 acc[8];
        #pragma unroll
        for (int nt = 0; nt < 8; ++nt) acc[nt] = (floatx4){0.f, 0.f, 0.f, 0.f};

        bf16x8 bh[8], bl[8];
        #pragma unroll
        for (int nt = 0; nt < 8; ++nt) bh[nt] = *(const bf16x8*)(pB[nt]);
        #pragma unroll
        for (int nt = 0; nt < 8; ++nt) bl[nt] = *(const bf16x8*)(pB[nt] + 1024);
        bf16x8 ah = *(const bf16x8*)&hhi[nof * PADP + quad * 8];
        bf16x8 al = *(const bf16x8*)&hlo[nof * PADP + quad * 8];

        #pragma unroll
        for (int kt = 0; kt < 8; ++kt) {
            bf16x8 nbh[8], nbl[8], nah, nal;
            if (kt < 7) {
                const size_t ko = (size_t)(kt + 1) * 2048;
                #pragma unroll
                for (int nt = 0; nt < 8; ++nt) nbh[nt] = *(const bf16x8*)(pB[nt] + ko);
                #pragma unroll
                for (int nt = 0; nt < 8; ++nt) nbl[nt] = *(const bf16x8*)(pB[nt] + ko + 1024);
                nah = *(const bf16x8*)&hhi[nof * PADP + (kt + 1) * 32 + quad * 8];
                nal = *(const bf16x8*)&hlo[nof * PADP + (kt + 1) * 32 + quad * 8];
            }
            #pragma unroll
            for (int nt = 0; nt < 8; ++nt) {
                acc[nt] = __builtin_amdgcn_mfma_f32_16x16x32_bf16(ah, bh[nt], acc[nt], 0, 0, 0);
                acc[nt] = __builtin_amdgcn_mfma_f32_16x16x32_bf16(al, bh[nt], acc[nt], 0, 0, 0);
                acc[nt] = __builtin_amdgcn_mfma_f32_16x16x32_bf16(ah, bl[nt], acc[nt], 0, 0, 0);
            }
            if (kt < 7) {
                #pragma unroll
                for (int nt = 0; nt < 8; ++nt) { bh[nt] = nbh[nt]; bl[nt] = nbl[nt]; }
                ah = nah; al = nal;
            }
        }

        __syncthreads();   // barrier1: all A-reads of hhi/hlo complete

        // ============ elementwise on C-fragments (in registers) =============
        const bool needy = (step >= WARM - 1);
        float inr[4];
        #pragma unroll
        for (int rg = 0; rg < 4; ++rg) {
            const int m = quad * 4 + rg;
            inr[rg] = (step < WARM) ? x_s[m * SEQ + step] : yb[m];
        }

        float p[4] = {0.f, 0.f, 0.f, 0.f};
        #pragma unroll
        for (int hf = 0; hf < 2; ++hf) {
            const int u = hf ? u1 : u0;
            const float fw = hf ? fcw1 : fcw0;
            #pragma unroll
            for (int rg = 0; rg < 4; ++rg) {
                const int m = quad * 4 + rg;
                float gi = acc[0 + hf][rg] + bbv[hf][0] + inr[rg] * wiv[hf][0];
                float gf = acc[2 + hf][rg] + bbv[hf][1] + inr[rg] * wiv[hf][1];
                float gg = acc[4 + hf][rg] + bbv[hf][2] + inr[rg] * wiv[hf][2];
                float go = acc[6 + hf][rg] + bbv[hf][3] + inr[rg] * wiv[hf][3];
                float ig = fast_sig(gi);
                float fg = fast_sig(gf);
                float gv = fast_tanh(gg);
                float og = fast_sig(go);
                float cn = fg * c[hf][rg] + ig * gv;
                c[hf][rg] = cn;
                float h  = og * fast_tanh(cn);
                short hi = f2bf(h);
                hhi[m * PADP + u] = hi;
                hlo[m * PADP + u] = f2bf(h - bf2f(hi));
                p[rg] += fw * h;
            }
        }

        if (needy) {
            #pragma unroll
            for (int off = 1; off < 16; off <<= 1) {
                #pragma unroll
                for (int rg = 0; rg < 4; ++rg) p[rg] += __shfl_xor(p[rg], off, 64);
            }
            if (nof == 0) {
                #pragma unroll
                for (int rg = 0; rg < 4; ++rg) part[wv][quad * 4 + rg] = p[rg];
            }
        }

        __syncthreads();   // barrier2: h-writes + partials visible

        if (needy && t < MROWS) {
            float yv = fcb0;
            #pragma unroll
            for (int k2 = 0; k2 < 8; ++k2) yv += part[k2][t];
            yb[t] = yv;
            if (step >= WARM)
                out[(r0 + t) * FLEN + (step - WARM)] = yv;
        }
    }
}

extern "C" void kernel_launch(void* const* d_in, const int* in_sizes, int n_in,
                              void* d_out, int out_size, void* d_ws, size_t ws_size,
                              hipStream_t stream) {
    const float* x    = (const float*)d_in[0];
    const float* h0   = (const float*)d_in[1];
    const float* c0   = (const float*)d_in[2];
    const float* W_ih = (const float*)d_in[3];
    const float* W_hh = (const float*)d_in[4];
    const float* b_ih = (const float*)d_in[5];
    const float* b_hh = (const float*)d_in[6];
    const float* fc_w = (const float*)d_in[7];
    const float* fc_b = (const float*)d_in[8];
    float* out = (float*)d_out;
    unsigned char* ws = (unsigned char*)d_ws;

    lstm_prep<<<1024, 256, 0, stream>>>(W_ih, W_hh, b_ih, b_hh, ws);
    lstm_mfma<<<128, 512, 0, stream>>>(x, h0, c0, ws, fc_w, fc_b, out);
}